// Round 1
// 88.671 us; speedup vs baseline: 1.0317x; 1.0317x over previous
//
#include <hip/hip_runtime.h>
#include <hip/hip_fp16.h>

typedef __attribute__((ext_vector_type(8)))  _Float16 half8;
typedef __attribute__((ext_vector_type(16))) float    f32x16;

#define B_   16
#define NPTS 4096                      // points per batch (N == M == 4096)

constexpr int BLK  = 1024;             // 16 waves per block
constexpr int WV   = 16;
constexpr int QPW  = 32;               // queries per wave (one MFMA N-dim)
constexpr int TSPL = 4;                // target splits (waves sharing a query group)
constexpr int QG   = WV / TSPL;        // 4 query groups per block
constexpr int QPB  = QG * QPW;         // 128 queries per block
constexpr int NQC  = NPTS / QPB;       // 32 query chunks
constexpr int TPS  = NPTS / TSPL;      // 1024 targets per split
constexpr int TPW  = TPS / 32;         // 32 tiles of 32 targets per wave
constexpr int NBLK = 2 * B_ * NQC;     // 1024 blocks

__device__ __forceinline__ float min3f(float a, float b, float c) {
    return fminf(fminf(a, b), c);      // -> v_min3_f32
}

// ------------------------------------------------------------------
// Occupancy-doubled restructure of the R7 kernel. Block = (dir, b,
// 128-query chunk) with 16 waves; wave (qg, ts) computes query group qg
// against target quarter ts. ALL 4096 targets staged once into 64 KB LDS
// (one barrier instead of four rounds). LDS footprint 66.6 KB -> exactly
// 2 blocks/CU -> 8 waves/SIMD (hardware cap, was 4). Per-tile math is
// identical to the proven kernel: A-frag rows [-2x,-2y,-2z,g2hi,g2lo,0,0,0],
// B-frag [x,y,z,1,1,0,0,0], one mfma_f32_32x32x16_f16 per tile ->
// D = 2(|g|^2 - 2 q.g); min3-tree folds 16 accs. Target-split mins are
// combined in-block via a 2 KB LDS buffer (min is associative -> exact).
__global__ __launch_bounds__(BLK, 8) void chamfer_mfma(
        const float* __restrict__ pred, const float* __restrict__ gt,
        float* __restrict__ accum, unsigned* __restrict__ counter,
        float* __restrict__ out) {
    const int qc  = blockIdx.x;
    const int b   = blockIdx.y;
    const int dir = blockIdx.z;
    const float* qsrc = dir ? gt   : pred;   // queries
    const float* tsrc = dir ? pred : gt;     // targets

    __shared__ uint4 sh[NPTS];               // 64 KB: all targets as A-frag rows
    __shared__ float sred[WV][QPW];          // 2 KB: per-wave per-query min d^2
    __shared__ float ps[2];

    const int tid  = threadIdx.x;
    const int lane = tid & 63;
    const int wv   = tid >> 6;
    const int m    = lane & 31;
    const int qg   = wv >> 2;                // query group 0..3
    const int ts   = wv & 3;                 // target split 0..3

    // ---- B fragment: this lane's query (col = lane&31 of its wave) ----
    const float* qp = qsrc + (b * NPTS + qc * QPB + qg * QPW + m) * 3;
    __half hqx = __float2half(qp[0]);
    __half hqy = __float2half(qp[1]);
    __half hqz = __float2half(qp[2]);
    float fqx = __half2float(hqx), fqy = __half2float(hqy), fqz = __half2float(hqz);
    const float q2 = fmaf(fqx, fqx, fmaf(fqy, fqy, fqz * fqz));
    uint4 bu;
    bu.x = (unsigned)__half_as_ushort(hqx) | ((unsigned)__half_as_ushort(hqy) << 16);
    bu.y = (unsigned)__half_as_ushort(hqz) | (0x3C00u << 16);   // {z, 1.0}
    bu.z = 0x3C00u;                                             // {1.0, 0}
    bu.w = 0u;
    const half8 bfrag = __builtin_bit_cast(half8, bu);

    f32x16 zero;
#pragma unroll
    for (int i = 0; i < 16; ++i) zero[i] = 0.0f;

    // ---- stage ALL 4096 targets as A-frag rows (once) ----
    const float* tp = tsrc + b * NPTS * 3;
#pragma unroll
    for (int k = 0; k < NPTS / BLK; ++k) {   // 4 points / thread
        int j = k * BLK + tid;
        __half hx = __float2half(tp[3 * j + 0]);
        __half hy = __float2half(tp[3 * j + 1]);
        __half hz = __float2half(tp[3 * j + 2]);
        float fx = __half2float(hx), fy = __half2float(hy), fz = __half2float(hz);
        float g2 = fmaf(fx, fx, fmaf(fy, fy, fz * fz));
        __half ax = __float2half(-2.0f * fx);
        __half ay = __float2half(-2.0f * fy);
        __half az = __float2half(-2.0f * fz);
        __half g2hi = __float2half(g2);
        __half g2lo = __float2half(g2 - __half2float(g2hi));
        uint4 w;
        w.x = (unsigned)__half_as_ushort(ax) | ((unsigned)__half_as_ushort(ay) << 16);
        w.y = (unsigned)__half_as_ushort(az) | ((unsigned)__half_as_ushort(g2hi) << 16);
        w.z = (unsigned)__half_as_ushort(g2lo);
        w.w = 0u;
        sh[j] = w;
    }
    __syncthreads();

    // ---- sweep this wave's 32 tiles; unroll 8 -> immediate-offset
    //      ds_reads, fine-grained lgkmcnt ----
    float mn = 1e30f;
#pragma unroll 8
    for (int t = 0; t < TPW; ++t) {
        uint4 au = sh[ts * TPS + t * 32 + m]; // lanes L, L+32 share addr (free 2-way)
        half8 afrag = __builtin_bit_cast(half8, au);
        f32x16 d = __builtin_amdgcn_mfma_f32_32x32x16_f16(afrag, bfrag, zero, 0, 0, 0);
        float m0 = min3f(d[0],  d[1],  d[2]);
        float m1 = min3f(d[3],  d[4],  d[5]);
        float m2 = min3f(d[6],  d[7],  d[8]);
        float m3 = min3f(d[9],  d[10], d[11]);
        float m4 = min3f(d[12], d[13], d[14]);
        float n0 = min3f(m0, m1, m2);
        float n1 = min3f(m3, m4, d[15]);
        mn = min3f(mn, n0, n1);
    }

    // rows split across lane halves: full 32-row min needs lane ^ 32
    float v  = fminf(mn, __shfl_xor(mn, 32));
    float dd = fmaxf(fmaf(0.5f, v, q2), 0.0f);   // undo K-dup, fold |q|^2 (d^2)
    if (lane < 32) sred[wv][m] = dd;             // lanes 32-63 hold duplicates
    __syncthreads();

    // ---- combine 4 target splits per query, sqrt, block-sum ----
    float s = 0.0f;
    if (wv < 2) {                                // threads 0..127 = 128 queries
        const int g  = tid >> 5;                 // query group 0..3
        const int mm = tid & 31;
        float d0 = fminf(sred[g * 4 + 0][mm], sred[g * 4 + 1][mm]);
        float d1 = fminf(sred[g * 4 + 2][mm], sred[g * 4 + 3][mm]);
        s = sqrtf(fminf(d0, d1));
        // butterfly sum over the 64 lanes of waves 0 and 1
#pragma unroll
        for (int off = 32; off; off >>= 1) s += __shfl_xor(s, off);
        if (lane == 0) ps[wv] = s;
    }
    __syncthreads();

    if (tid == 0) {
        float bs = ps[0] + ps[1];
        atomicAdd(accum, bs);
        __threadfence();
        if (atomicAdd(counter, 1u) == NBLK - 1) {   // last block finalizes
            float total = atomicAdd(accum, 0.0f);   // coherent read
            float loss  = total * (1.0f / (float)(B_ * NPTS));
            out[0] = loss;          // WEIGHT * loss, WEIGHT = 1
            out[1] = loss;          // helper_loss
            out[2] = 0.1f * loss;   // helper_cderr = p1 chamfer * xyz_unit
        }
    }
}

// ------------------------------------------------------------------
extern "C" void kernel_launch(void* const* d_in, const int* in_sizes, int n_in,
                              void* d_out, int out_size, void* d_ws, size_t ws_size,
                              hipStream_t stream) {
    const float* pred = (const float*)d_in[0];
    const float* gt   = (const float*)d_in[1];
    float*    out     = (float*)d_out;
    float*    accum   = (float*)d_ws;
    unsigned* counter = (unsigned*)d_ws + 1;

    hipMemsetAsync(d_ws, 0, 8, stream);
    chamfer_mfma<<<dim3(NQC, B_, 2), BLK, 0, stream>>>(pred, gt, accum, counter, out);
}

// Round 2
// 79.382 us; speedup vs baseline: 1.1524x; 1.1170x over previous
//
#include <hip/hip_runtime.h>
#include <hip/hip_fp16.h>

typedef __attribute__((ext_vector_type(8)))  _Float16 half8;
typedef __attribute__((ext_vector_type(16))) float    f32x16;

#define B_   16
#define NPTS 4096                      // points per batch (N == M == 4096)

constexpr int BLK  = 512;              // 8 waves per block
constexpr int WV   = 8;
constexpr int QF   = 2;                // query fragments per wave (64 queries)
constexpr int QPW  = 32 * QF;          // 64 queries per wave
constexpr int TSPL = 2;                // target splits (waves sharing a query group)
constexpr int QG   = WV / TSPL;        // 4 query groups per block
constexpr int QPB  = QG * QPW;         // 256 queries per block
constexpr int NQC  = NPTS / QPB;       // 16 query chunks
constexpr int TPS  = NPTS / TSPL;      // 2048 targets per split
constexpr int TPW  = TPS / 32;         // 64 tiles of 32 targets per wave
constexpr int NBLK = 2 * B_ * NQC;     // 512 blocks (2 per CU)

__device__ __forceinline__ float min3f(float a, float b, float c) {
    return fminf(fminf(a, b), c);      // -> v_min3_f32
}

// ------------------------------------------------------------------
// R2: attack the per-wave dependent chain (R1 showed TLP 4->8 waves/SIMD
// is neutral; VGPR_Count=52 means the compiler was register-starved by
// __launch_bounds__(1024,8) and serialized ds_read->MFMA->min-tree).
//  * 2 query fragments per wave: each staged A-tile ds_read feeds 2
//    independent MFMAs + 2 min-trees -> half the LDS ops per MFMA,
//    double the independent work per load.
//  * __launch_bounds__(512,4) -> 128-VGPR budget, room for multiple
//    f32x16 results in flight.
//  * 512 blocks re-stage targets (vs 1024) -> staging work halves.
// Math identical to proven kernel: A-row [-2x,-2y,-2z,g2hi,g2lo,0,0,0],
// B-frag [x,y,z,1,1,0,0,0] -> D = 2(|g|^2 - 2 q.g); d^2 = 0.5*minD+|q|^2.
__global__ __launch_bounds__(BLK, 4) void chamfer_mfma(
        const float* __restrict__ pred, const float* __restrict__ gt,
        float* __restrict__ accum, unsigned* __restrict__ counter,
        float* __restrict__ out) {
    const int qc  = blockIdx.x;
    const int b   = blockIdx.y;
    const int dir = blockIdx.z;
    const float* qsrc = dir ? gt   : pred;   // queries
    const float* tsrc = dir ? pred : gt;     // targets

    __shared__ uint4 sh[NPTS];               // 64 KB: all targets as A-frag rows
    __shared__ float sred[WV][QPW];          // 2 KB: per-wave per-query min d^2
    __shared__ float ps[QG];

    const int tid  = threadIdx.x;
    const int lane = tid & 63;
    const int wv   = tid >> 6;
    const int m    = lane & 31;
    const int qg   = wv >> 1;                // query group 0..3
    const int ts   = wv & 1;                 // target split 0..1

    // ---- B fragments: this lane's two queries (cols m and m+32) ----
    const float* qbase = qsrc + (b * NPTS + qc * QPB + qg * QPW) * 3;
    half8 bfrag[QF];
    float q2[QF];
#pragma unroll
    for (int f = 0; f < QF; ++f) {
        const float* qp = qbase + (f * 32 + m) * 3;
        __half hqx = __float2half(qp[0]);
        __half hqy = __float2half(qp[1]);
        __half hqz = __float2half(qp[2]);
        float fqx = __half2float(hqx), fqy = __half2float(hqy), fqz = __half2float(hqz);
        q2[f] = fmaf(fqx, fqx, fmaf(fqy, fqy, fqz * fqz));
        uint4 bu;
        bu.x = (unsigned)__half_as_ushort(hqx) | ((unsigned)__half_as_ushort(hqy) << 16);
        bu.y = (unsigned)__half_as_ushort(hqz) | (0x3C00u << 16);   // {z, 1.0}
        bu.z = 0x3C00u;                                             // {1.0, 0}
        bu.w = 0u;
        bfrag[f] = __builtin_bit_cast(half8, bu);
    }

    f32x16 zero;
#pragma unroll
    for (int i = 0; i < 16; ++i) zero[i] = 0.0f;

    // ---- stage ALL 4096 targets as A-frag rows (once) ----
    const float* tp = tsrc + b * NPTS * 3;
#pragma unroll
    for (int k = 0; k < NPTS / BLK; ++k) {   // 8 points / thread
        int j = k * BLK + tid;
        __half hx = __float2half(tp[3 * j + 0]);
        __half hy = __float2half(tp[3 * j + 1]);
        __half hz = __float2half(tp[3 * j + 2]);
        float fx = __half2float(hx), fy = __half2float(hy), fz = __half2float(hz);
        float g2 = fmaf(fx, fx, fmaf(fy, fy, fz * fz));
        __half ax = __float2half(-2.0f * fx);
        __half ay = __float2half(-2.0f * fy);
        __half az = __float2half(-2.0f * fz);
        __half g2hi = __float2half(g2);
        __half g2lo = __float2half(g2 - __half2float(g2hi));
        uint4 w;
        w.x = (unsigned)__half_as_ushort(ax) | ((unsigned)__half_as_ushort(ay) << 16);
        w.y = (unsigned)__half_as_ushort(az) | ((unsigned)__half_as_ushort(g2hi) << 16);
        w.z = (unsigned)__half_as_ushort(g2lo);
        w.w = 0u;
        sh[j] = w;
    }
    __syncthreads();

    // ---- sweep this wave's 64 tiles; each ds_read feeds 2 MFMAs ----
    float mn0 = 1e30f, mn1 = 1e30f;
#pragma unroll 8
    for (int t = 0; t < TPW; ++t) {
        uint4 au = sh[ts * TPS + t * 32 + m]; // lanes L, L+32 share addr (free 2-way)
        half8 afrag = __builtin_bit_cast(half8, au);
        f32x16 d0 = __builtin_amdgcn_mfma_f32_32x32x16_f16(afrag, bfrag[0], zero, 0, 0, 0);
        f32x16 d1 = __builtin_amdgcn_mfma_f32_32x32x16_f16(afrag, bfrag[1], zero, 0, 0, 0);
        {
            float a0 = min3f(d0[0],  d0[1],  d0[2]);
            float a1 = min3f(d0[3],  d0[4],  d0[5]);
            float a2 = min3f(d0[6],  d0[7],  d0[8]);
            float a3 = min3f(d0[9],  d0[10], d0[11]);
            float a4 = min3f(d0[12], d0[13], d0[14]);
            float n0 = min3f(a0, a1, a2);
            float n1 = min3f(a3, a4, d0[15]);
            mn0 = min3f(mn0, n0, n1);
        }
        {
            float a0 = min3f(d1[0],  d1[1],  d1[2]);
            float a1 = min3f(d1[3],  d1[4],  d1[5]);
            float a2 = min3f(d1[6],  d1[7],  d1[8]);
            float a3 = min3f(d1[9],  d1[10], d1[11]);
            float a4 = min3f(d1[12], d1[13], d1[14]);
            float n0 = min3f(a0, a1, a2);
            float n1 = min3f(a3, a4, d1[15]);
            mn1 = min3f(mn1, n0, n1);
        }
    }

    // rows split across lane halves: full 32-row min needs lane ^ 32
    float v0 = fminf(mn0, __shfl_xor(mn0, 32));
    float v1 = fminf(mn1, __shfl_xor(mn1, 32));
    float dd0 = fmaxf(fmaf(0.5f, v0, q2[0]), 0.0f);  // undo K-dup, fold |q|^2
    float dd1 = fmaxf(fmaf(0.5f, v1, q2[1]), 0.0f);
    if (lane < 32) {                                 // lanes 32-63 hold duplicates
        sred[wv][m]      = dd0;
        sred[wv][m + 32] = dd1;
    }
    __syncthreads();

    // ---- combine 2 target splits per query, sqrt, block-sum ----
    float s = 0.0f;
    if (wv < QG) {                               // threads 0..255 = 256 queries
        const int g  = wv;                       // query group 0..3
        const int mm = lane;                     // query within group 0..63
        float d = fminf(sred[g * 2 + 0][mm], sred[g * 2 + 1][mm]);
        s = sqrtf(d);
        // butterfly sum over this wave's 64 lanes
#pragma unroll
        for (int off = 32; off; off >>= 1) s += __shfl_xor(s, off);
        if (lane == 0) ps[g] = s;
    }
    __syncthreads();

    if (tid == 0) {
        float bs = ps[0] + ps[1] + ps[2] + ps[3];
        atomicAdd(accum, bs);
        __threadfence();
        if (atomicAdd(counter, 1u) == NBLK - 1) {   // last block finalizes
            float total = atomicAdd(accum, 0.0f);   // coherent read
            float loss  = total * (1.0f / (float)(B_ * NPTS));
            out[0] = loss;          // WEIGHT * loss, WEIGHT = 1
            out[1] = loss;          // helper_loss
            out[2] = 0.1f * loss;   // helper_cderr = p1 chamfer * xyz_unit
        }
    }
}

// ------------------------------------------------------------------
extern "C" void kernel_launch(void* const* d_in, const int* in_sizes, int n_in,
                              void* d_out, int out_size, void* d_ws, size_t ws_size,
                              hipStream_t stream) {
    const float* pred = (const float*)d_in[0];
    const float* gt   = (const float*)d_in[1];
    float*    out     = (float*)d_out;
    float*    accum   = (float*)d_ws;
    unsigned* counter = (unsigned*)d_ws + 1;

    hipMemsetAsync(d_ws, 0, 8, stream);
    chamfer_mfma<<<dim3(NQC, B_, 2), BLK, 0, stream>>>(pred, gt, accum, counter, out);
}

// Round 4
// 79.251 us; speedup vs baseline: 1.1543x; 1.0017x over previous
//
#include <hip/hip_runtime.h>
#include <hip/hip_fp16.h>

typedef __attribute__((ext_vector_type(8)))  _Float16 half8;
typedef __attribute__((ext_vector_type(16))) float    f32x16;

#define B_   16
#define NPTS 4096                      // points per batch (N == M == 4096)

constexpr int BLK  = 512;              // 8 waves per block
constexpr int WV   = 8;
constexpr int QF   = 2;                // query fragments per wave (64 queries)
constexpr int TF   = 2;                // target tiles per loop step
constexpr int QPW  = 32 * QF;          // 64 queries per wave
constexpr int TSPL = 2;                // target splits (waves sharing a query group)
constexpr int QG   = WV / TSPL;        // 4 query groups per block
constexpr int QPB  = QG * QPW;         // 256 queries per block
constexpr int NQC  = NPTS / QPB;       // 16 query chunks
constexpr int TPS  = NPTS / TSPL;      // 2048 targets per split
constexpr int TPW  = TPS / 32;         // 64 tiles of 32 targets per wave
constexpr int NIT  = TPW / TF;         // 32 loop steps (2 tiles each)
constexpr int NBLK = 2 * B_ * NQC;     // 512 blocks (2 per CU)

__device__ __forceinline__ float min3f(float a, float b, float c) {
    return fminf(fminf(a, b), c);      // -> v_min3_f32
}

__device__ __forceinline__ float tree16(const f32x16& d) {
    float a0 = min3f(d[0],  d[1],  d[2]);
    float a1 = min3f(d[3],  d[4],  d[5]);
    float a2 = min3f(d[6],  d[7],  d[8]);
    float a3 = min3f(d[9],  d[10], d[11]);
    float a4 = min3f(d[12], d[13], d[14]);
    return fminf(min3f(a0, a1, a2), min3f(a3, a4, d[15]));
}

// ------------------------------------------------------------------
// R3 (recompiled): deepen per-wave ILP (R2's 2-MFMA/iter bought 25%;
// still latency bound at ~9x the pipe floors). Each loop step reads TWO
// A-tiles and issues FOUR independent MFMAs (2 tiles x 2 query frags)
// + 4 min-trees. 4 independent dependency streams per step, half the
// loop overhead per MFMA. Register cost ~110 < 128 cap of (512,4).
// Math identical to proven kernel: A-row [-2x,-2y,-2z,g2hi,g2lo,0,0,0],
// B-frag [x,y,z,1,1,0,0,0] -> D = 2(|g|^2 - 2 q.g); d^2 = 0.5*minD+|q|^2.
__global__ __launch_bounds__(BLK, 4) void chamfer_mfma(
        const float* __restrict__ pred, const float* __restrict__ gt,
        float* __restrict__ accum, unsigned* __restrict__ counter,
        float* __restrict__ out) {
    const int qc  = blockIdx.x;
    const int b   = blockIdx.y;
    const int dir = blockIdx.z;
    const float* qsrc = dir ? gt   : pred;   // queries
    const float* tsrc = dir ? pred : gt;     // targets

    __shared__ uint4 sh[NPTS];               // 64 KB: all targets as A-frag rows
    __shared__ float sred[WV][QPW];          // 2 KB: per-wave per-query min d^2
    __shared__ float ps[QG];

    const int tid  = threadIdx.x;
    const int lane = tid & 63;
    const int wv   = tid >> 6;
    const int m    = lane & 31;
    const int qg   = wv >> 1;                // query group 0..3
    const int ts   = wv & 1;                 // target split 0..1

    // ---- B fragments: this lane's two queries (cols m and m+32) ----
    const float* qbase = qsrc + (b * NPTS + qc * QPB + qg * QPW) * 3;
    half8 bfrag[QF];
    float q2[QF];
#pragma unroll
    for (int f = 0; f < QF; ++f) {
        const float* qp = qbase + (f * 32 + m) * 3;
        __half hqx = __float2half(qp[0]);
        __half hqy = __float2half(qp[1]);
        __half hqz = __float2half(qp[2]);
        float fqx = __half2float(hqx), fqy = __half2float(hqy), fqz = __half2float(hqz);
        q2[f] = fmaf(fqx, fqx, fmaf(fqy, fqy, fqz * fqz));
        uint4 bu;
        bu.x = (unsigned)__half_as_ushort(hqx) | ((unsigned)__half_as_ushort(hqy) << 16);
        bu.y = (unsigned)__half_as_ushort(hqz) | (0x3C00u << 16);   // {z, 1.0}
        bu.z = 0x3C00u;                                             // {1.0, 0}
        bu.w = 0u;
        bfrag[f] = __builtin_bit_cast(half8, bu);
    }

    f32x16 zero;
#pragma unroll
    for (int i = 0; i < 16; ++i) zero[i] = 0.0f;

    // ---- stage ALL 4096 targets as A-frag rows (once) ----
    const float* tp = tsrc + b * NPTS * 3;
#pragma unroll
    for (int k = 0; k < NPTS / BLK; ++k) {   // 8 points / thread
        int j = k * BLK + tid;
        __half hx = __float2half(tp[3 * j + 0]);
        __half hy = __float2half(tp[3 * j + 1]);
        __half hz = __float2half(tp[3 * j + 2]);
        float fx = __half2float(hx), fy = __half2float(hy), fz = __half2float(hz);
        float g2 = fmaf(fx, fx, fmaf(fy, fy, fz * fz));
        __half ax = __float2half(-2.0f * fx);
        __half ay = __float2half(-2.0f * fy);
        __half az = __float2half(-2.0f * fz);
        __half g2hi = __float2half(g2);
        __half g2lo = __float2half(g2 - __half2float(g2hi));
        uint4 w;
        w.x = (unsigned)__half_as_ushort(ax) | ((unsigned)__half_as_ushort(ay) << 16);
        w.y = (unsigned)__half_as_ushort(az) | ((unsigned)__half_as_ushort(g2hi) << 16);
        w.z = (unsigned)__half_as_ushort(g2lo);
        w.w = 0u;
        sh[j] = w;
    }
    __syncthreads();

    // ---- sweep this wave's 64 tiles, 2 tiles x 2 qfrags per step ----
    const uint4* shp = sh + ts * TPS + m;    // lane base (lanes L, L+32 share addr)
    float mn0 = 1e30f, mn1 = 1e30f;
#pragma unroll 8
    for (int t = 0; t < NIT; ++t) {
        uint4 au0 = shp[t * 64];             // tile 2t   (byte off t*1024)
        uint4 au1 = shp[t * 64 + 32];        // tile 2t+1 (byte off t*1024+512)
        half8 a0 = __builtin_bit_cast(half8, au0);
        half8 a1 = __builtin_bit_cast(half8, au1);
        f32x16 d00 = __builtin_amdgcn_mfma_f32_32x32x16_f16(a0, bfrag[0], zero, 0, 0, 0);
        f32x16 d01 = __builtin_amdgcn_mfma_f32_32x32x16_f16(a0, bfrag[1], zero, 0, 0, 0);
        f32x16 d10 = __builtin_amdgcn_mfma_f32_32x32x16_f16(a1, bfrag[0], zero, 0, 0, 0);
        f32x16 d11 = __builtin_amdgcn_mfma_f32_32x32x16_f16(a1, bfrag[1], zero, 0, 0, 0);
        float t00 = tree16(d00);
        float t01 = tree16(d01);
        float t10 = tree16(d10);
        float t11 = tree16(d11);
        mn0 = min3f(mn0, t00, t10);
        mn1 = min3f(mn1, t01, t11);
    }

    // rows split across lane halves: full 32-row min needs lane ^ 32
    float v0 = fminf(mn0, __shfl_xor(mn0, 32));
    float v1 = fminf(mn1, __shfl_xor(mn1, 32));
    float dd0 = fmaxf(fmaf(0.5f, v0, q2[0]), 0.0f);  // undo K-dup, fold |q|^2
    float dd1 = fmaxf(fmaf(0.5f, v1, q2[1]), 0.0f);
    if (lane < 32) {                                 // lanes 32-63 hold duplicates
        sred[wv][m]      = dd0;
        sred[wv][m + 32] = dd1;
    }
    __syncthreads();

    // ---- combine 2 target splits per query, sqrt, block-sum ----
    float s = 0.0f;
    if (wv < QG) {                               // threads 0..255 = 256 queries
        const int g  = wv;                       // query group 0..3
        const int mm = lane;                     // query within group 0..63
        float d = fminf(sred[g * 2 + 0][mm], sred[g * 2 + 1][mm]);
        s = sqrtf(d);
        // butterfly sum over this wave's 64 lanes
#pragma unroll
        for (int off = 32; off; off >>= 1) s += __shfl_xor(s, off);
        if (lane == 0) ps[g] = s;
    }
    __syncthreads();

    if (tid == 0) {
        float bs = ps[0] + ps[1] + ps[2] + ps[3];
        atomicAdd(accum, bs);
        __threadfence();
        if (atomicAdd(counter, 1u) == NBLK - 1) {   // last block finalizes
            float total = atomicAdd(accum, 0.0f);   // coherent read
            float loss  = total * (1.0f / (float)(B_ * NPTS));
            out[0] = loss;          // WEIGHT * loss, WEIGHT = 1
            out[1] = loss;          // helper_loss
            out[2] = 0.1f * loss;   // helper_cderr = p1 chamfer * xyz_unit
        }
    }
}

// ------------------------------------------------------------------
extern "C" void kernel_launch(void* const* d_in, const int* in_sizes, int n_in,
                              void* d_out, int out_size, void* d_ws, size_t ws_size,
                              hipStream_t stream) {
    const float* pred = (const float*)d_in[0];
    const float* gt   = (const float*)d_in[1];
    float*    out     = (float*)d_out;
    float*    accum   = (float*)d_ws;
    unsigned* counter = (unsigned*)d_ws + 1;

    hipMemsetAsync(d_ws, 0, 8, stream);
    chamfer_mfma<<<dim3(NQC, B_, 2), BLK, 0, stream>>>(pred, gt, accum, counter, out);
}